// Round 1
// baseline (24.744 us; speedup 1.0000x reference)
//
#include <hip/hip_runtime.h>

// FastTextItout: embedding gather + linear LIF scan (collapses to weighted sum)
// + relu + fc dot. B=16384, T=64, VOCAB=1001, EMB=16, HID=1024.
//
// out[b] = sum_h relu( xw[b,:] @ W[:,h] + S*(lif_b[h]+beta) ) * fc_w[h] + fc_b
// with xw[b,:] = sum_t alpha^(63-t) * emb[xis[b,t],:],  S = sum_{k<64} alpha^k.

#define BB      16384
#define TT      64
#define EMB     16
#define HID     1024
#define ROWS    32      // rows per block
#define NTHR    256     // threads per block
#define HPT     4       // h-columns per thread (NTHR*HPT == HID)
#define NBLK    (BB / ROWS)   // 512 blocks

__global__ __launch_bounds__(NTHR, 2)
void fasttext_itout_kernel(const int* __restrict__ xis,
                           const float* __restrict__ emb,
                           const float* __restrict__ lif_w,
                           const float* __restrict__ lif_b,
                           const float* __restrict__ fc_w,
                           const float* __restrict__ fc_b,
                           const float* __restrict__ alpha_p,
                           const float* __restrict__ beta_p,
                           float* __restrict__ out)
{
    const int tid  = threadIdx.x;
    const int row0 = blockIdx.x * ROWS;
    const float alpha = alpha_p[0];
    const float beta  = beta_p[0];

    __shared__ float xw_lds[ROWS][EMB];   // weighted embedding sums
    __shared__ float wred[ROWS][4];       // per-wave partial outputs

    // ---- geometric-sum scale S = sum_{k=0}^{T-1} alpha^k (term-by-term, f32)
    float S = 0.f;
    {
        float pk = 1.f;
        for (int k = 0; k < TT; ++k) { S += pk; pk *= alpha; }
    }

    // ---- W, bias, fc_w into registers. Thread owns h = tid + 256*j.
    float wreg[EMB][HPT];
    float biasr[HPT], fcwr[HPT];
    #pragma unroll
    for (int j = 0; j < HPT; ++j) {
        const int h = tid + j * NTHR;
        biasr[j] = S * (lif_b[h] + beta);
        fcwr[j]  = fc_w[h];
        #pragma unroll
        for (int e = 0; e < EMB; ++e)
            wreg[e][j] = lif_w[e * HID + h];
    }

    // ---- phase 1: xw[r][e] = sum_t alpha^(63-t) emb[xis[r,t]][e]
    // 256 threads cover 2*(16 rows x 16 e): thread -> (r, e) and (r+16, e).
    {
        const int r = tid >> 4;          // 0..15
        const int e = tid & 15;
        const int4* xa = (const int4*)(xis + (size_t)(row0 + r)      * TT);
        const int4* xb = (const int4*)(xis + (size_t)(row0 + r + 16) * TT);
        float pa = 0.f, pb = 0.f;
        float w = 1.f;                   // weight for t=63, multiplied by alpha going down
        for (int t4 = TT / 4 - 1; t4 >= 0; --t4) {
            const int4 ia = xa[t4];
            const int4 ib = xb[t4];
            pa += w * emb[(size_t)ia.w * EMB + e];
            pb += w * emb[(size_t)ib.w * EMB + e];
            w *= alpha;
            pa += w * emb[(size_t)ia.z * EMB + e];
            pb += w * emb[(size_t)ib.z * EMB + e];
            w *= alpha;
            pa += w * emb[(size_t)ia.y * EMB + e];
            pb += w * emb[(size_t)ib.y * EMB + e];
            w *= alpha;
            pa += w * emb[(size_t)ia.x * EMB + e];
            pb += w * emb[(size_t)ib.x * EMB + e];
            w *= alpha;
        }
        xw_lds[r][e]      = pa;
        xw_lds[r + 16][e] = pb;
    }
    __syncthreads();

    // ---- phase 2: per row, acc_h = bias + xw . W[:,h]; out += relu(acc)*fcw
    const int wave = tid >> 6;
    const int lane = tid & 63;
    for (int r = 0; r < ROWS; ++r) {
        const float4 x0 = ((const float4*)xw_lds[r])[0];
        const float4 x1 = ((const float4*)xw_lds[r])[1];
        const float4 x2 = ((const float4*)xw_lds[r])[2];
        const float4 x3 = ((const float4*)xw_lds[r])[3];
        const float xw[EMB] = { x0.x, x0.y, x0.z, x0.w,
                                x1.x, x1.y, x1.z, x1.w,
                                x2.x, x2.y, x2.z, x2.w,
                                x3.x, x3.y, x3.z, x3.w };
        float acc[HPT];
        #pragma unroll
        for (int j = 0; j < HPT; ++j) acc[j] = biasr[j];
        #pragma unroll
        for (int e = 0; e < EMB; ++e) {
            #pragma unroll
            for (int j = 0; j < HPT; ++j)
                acc[j] += xw[e] * wreg[e][j];
        }
        float pr = 0.f;
        #pragma unroll
        for (int j = 0; j < HPT; ++j)
            pr += fmaxf(acc[j], 0.f) * fcwr[j];
        // wave-wide reduce (64 lanes)
        #pragma unroll
        for (int o = 32; o > 0; o >>= 1)
            pr += __shfl_xor(pr, o);
        if (lane == 0) wred[r][wave] = pr;
    }
    __syncthreads();

    if (tid < ROWS) {
        const float v = wred[tid][0] + wred[tid][1] + wred[tid][2] + wred[tid][3]
                        + fc_b[0];
        out[row0 + tid] = v;
    }
}

extern "C" void kernel_launch(void* const* d_in, const int* in_sizes, int n_in,
                              void* d_out, int out_size, void* d_ws, size_t ws_size,
                              hipStream_t stream) {
    const int*   xis   = (const int*)d_in[0];
    const float* emb   = (const float*)d_in[1];
    const float* lif_w = (const float*)d_in[2];
    const float* lif_b = (const float*)d_in[3];
    const float* fc_w  = (const float*)d_in[4];
    const float* fc_b  = (const float*)d_in[5];
    const float* alpha = (const float*)d_in[6];
    const float* beta  = (const float*)d_in[7];
    float* out = (float*)d_out;

    fasttext_itout_kernel<<<NBLK, NTHR, 0, stream>>>(
        xis, emb, lif_w, lif_b, fc_w, fc_b, alpha, beta, out);
}

// Round 2
// 15.208 us; speedup vs baseline: 1.6270x; 1.6270x over previous
//
#include <hip/hip_runtime.h>
#include <hip/hip_bf16.h>

// FastTextItout, MFMA version.
// out[b] = sum_h relu( xw[b,:] @ W[:,h] + S*(lif_b[h]+beta) ) * fc_w[h] + fc_b
// xw[b,:] = sum_t alpha^(63-t) * emb[xis[b,t],:],  S = sum_{k<64} alpha^k.
// B=16384, T=64, EMB=16 (K, padded to 32 for MFMA), HID=1024, VOCAB=1001.

#define BB    16384
#define TT    64
#define EMBD  16
#define HIDD  1024
#define NVOC  1001
#define ROWS  64            // rows per block
#define NTHR  512           // 8 waves
#define NBLK  (BB / ROWS)   // 256 blocks = 1/CU
#define EPAD  20            // padded bf16 elems per emb row in LDS (40 B)
#define HTPW  8             // h-tiles per wave (8 waves x 8 = 64 tiles = 1024 h)

typedef __attribute__((ext_vector_type(8))) short          frag_ab;
typedef __attribute__((ext_vector_type(4))) float          frag_cd;
typedef __attribute__((ext_vector_type(4))) unsigned short us4;

__device__ __forceinline__ float bf2f(unsigned short u) {
    union { unsigned int i; float f; } x; x.i = ((unsigned int)u) << 16; return x.f;
}
__device__ __forceinline__ unsigned short f2b(float f) {
    __hip_bfloat16 h = __float2bfloat16(f);   // RNE
    return __builtin_bit_cast(unsigned short, h);
}

__global__ __launch_bounds__(NTHR)
void ftt_kernel(const int* __restrict__ xis, const float* __restrict__ emb,
                const float* __restrict__ lif_w, const float* __restrict__ lif_b,
                const float* __restrict__ fc_w, const float* __restrict__ fc_b,
                const float* __restrict__ alpha_p, const float* __restrict__ beta_p,
                float* __restrict__ out)
{
    __shared__ unsigned short embl[NVOC * EPAD];  // 40040 B, bf16 emb, padded rows
    __shared__ unsigned short xwb[ROWS * EMBD];   // 2048 B, bf16 XW
    __shared__ float red[ROWS / 16][8][16];       // 2048 B, per-wave partials

    const int tid  = threadIdx.x;
    const int row0 = blockIdx.x * ROWS;
    const float alpha = alpha_p[0];
    const float beta  = beta_p[0];

    // S = sum_{k<64} alpha^k ; a32 = alpha^32
    float S = 0.f, pk = 1.f, a32 = 0.f;
    #pragma unroll 1
    for (int k = 0; k < TT; ++k) { if (k == 32) a32 = pk; S += pk; pk *= alpha; }

    // ---- stage emb f32 -> bf16 into LDS (rows padded to EPAD)
    for (int v = tid; v < NVOC; v += NTHR) {
        const float4* ep = (const float4*)(emb + (size_t)v * EMBD);
        #pragma unroll
        for (int q = 0; q < 4; ++q) {
            const float4 e = ep[q];
            us4 u = { f2b(e.x), f2b(e.y), f2b(e.z), f2b(e.w) };
            *(us4*)&embl[v * EPAD + q * 4] = u;
        }
    }

    // ---- per-wave W fragments / bias / fc_w (global loads, no LDS dep)
    const int lane = tid & 63;
    const int wave = tid >> 6;
    const int nn   = lane & 15;   // MFMA col (h within tile)
    const int kg   = lane >> 4;   // k-group 0..3 (k = kg*8+i; k>=16 is zero pad)

    frag_ab bfrag[HTPW];
    float   biasr[HTPW], fcwr[HTPW];
    #pragma unroll
    for (int j = 0; j < HTPW; ++j) {
        const int h = wave * (HTPW * 16) + j * 16 + nn;
        biasr[j] = S * (lif_b[h] + beta);
        fcwr[j]  = fc_w[h];
        frag_ab b = {0, 0, 0, 0, 0, 0, 0, 0};
        if (kg < 2) {
            #pragma unroll
            for (int i = 0; i < 8; ++i) {
                const int k = kg * 8 + i;
                b[i] = (short)f2b(lif_w[k * HIDD + h]);
            }
        }
        bfrag[j] = b;
    }
    __syncthreads();   // embl ready

    // ---- gather: xw[r][e] = sum_t alpha^(63-t) * emb[xis[r][t]][e]
    {
        const int r   = tid >> 3;     // 0..63
        const int sub = tid & 7;
        const int q   = sub & 3;      // e-quad (4 elems)
        const int H   = sub >> 2;     // t-half (32 t each)
        const int4* xp = (const int4*)(xis + (size_t)(row0 + r) * TT + H * 32);
        float px = 0.f, py = 0.f, pz = 0.f, pw = 0.f;
        float w = 1.f;                // local weight, descending t within half
        #pragma unroll
        for (int c = 7; c >= 0; --c) {
            const int4 iv = xp[c];
            { const us4 e = *(const us4*)&embl[iv.w * EPAD + q * 4];
              px += w * bf2f(e.x); py += w * bf2f(e.y);
              pz += w * bf2f(e.z); pw += w * bf2f(e.w); w *= alpha; }
            { const us4 e = *(const us4*)&embl[iv.z * EPAD + q * 4];
              px += w * bf2f(e.x); py += w * bf2f(e.y);
              pz += w * bf2f(e.z); pw += w * bf2f(e.w); w *= alpha; }
            { const us4 e = *(const us4*)&embl[iv.y * EPAD + q * 4];
              px += w * bf2f(e.x); py += w * bf2f(e.y);
              pz += w * bf2f(e.z); pw += w * bf2f(e.w); w *= alpha; }
            { const us4 e = *(const us4*)&embl[iv.x * EPAD + q * 4];
              px += w * bf2f(e.x); py += w * bf2f(e.y);
              pz += w * bf2f(e.z); pw += w * bf2f(e.w); w *= alpha; }
        }
        const float sc = H ? 1.f : a32;   // lower half contributes alpha^32 * partial
        px *= sc; py *= sc; pz *= sc; pw *= sc;
        // combine the two t-halves (lane bit 2 == H)
        px += __shfl_xor(px, 4); py += __shfl_xor(py, 4);
        pz += __shfl_xor(pz, 4); pw += __shfl_xor(pw, 4);
        if (H == 0) {
            us4 u = { f2b(px), f2b(py), f2b(pz), f2b(pw) };
            *(us4*)&xwb[r * EMBD + q * 4] = u;
        }
    }
    __syncthreads();   // xwb ready

    // ---- MFMA: per 16-row tile, all 64 h-tiles (8 per wave), fused epilogue
    #pragma unroll
    for (int rt = 0; rt < ROWS / 16; ++rt) {
        frag_ab a = {0, 0, 0, 0, 0, 0, 0, 0};
        if (kg < 2)  // k = kg*8..kg*8+7 < 16 real, kg>=2 stays zero (K padding)
            a = *(const frag_ab*)&xwb[(rt * 16 + nn) * EMBD + kg * 8];
        frag_cd pacc = {0.f, 0.f, 0.f, 0.f};
        #pragma unroll
        for (int j = 0; j < HTPW; ++j) {
            frag_cd z = {0.f, 0.f, 0.f, 0.f};
            frag_cd c = __builtin_amdgcn_mfma_f32_16x16x32_bf16(a, bfrag[j], z, 0, 0, 0);
            #pragma unroll
            for (int x = 0; x < 4; ++x)
                pacc[x] += fmaxf(c[x] + biasr[j], 0.f) * fcwr[j];
        }
        // reduce over the 16 n-lanes (masks 1,2,4,8 stay within the kg group)
        #pragma unroll
        for (int m = 1; m <= 8; m <<= 1) {
            #pragma unroll
            for (int x = 0; x < 4; ++x) pacc[x] += __shfl_xor(pacc[x], m);
        }
        if (nn == 0) {
            #pragma unroll
            for (int x = 0; x < 4; ++x)
                red[rt][wave][kg * 4 + x] = pacc[x];   // row m = kg*4+x
        }
    }
    __syncthreads();

    if (tid < ROWS) {
        float s = fc_b[0];
        #pragma unroll
        for (int w2 = 0; w2 < 8; ++w2) s += red[tid >> 4][w2][tid & 15];
        out[row0 + tid] = s;
    }
}

extern "C" void kernel_launch(void* const* d_in, const int* in_sizes, int n_in,
                              void* d_out, int out_size, void* d_ws, size_t ws_size,
                              hipStream_t stream) {
    const int*   xis   = (const int*)d_in[0];
    const float* emb   = (const float*)d_in[1];
    const float* lif_w = (const float*)d_in[2];
    const float* lif_b = (const float*)d_in[3];
    const float* fc_w  = (const float*)d_in[4];
    const float* fc_b  = (const float*)d_in[5];
    const float* alpha = (const float*)d_in[6];
    const float* beta  = (const float*)d_in[7];
    float* out = (float*)d_out;

    ftt_kernel<<<NBLK, NTHR, 0, stream>>>(
        xis, emb, lif_w, lif_b, fc_w, fc_b, alpha, beta, out);
}